// Round 5
// baseline (300.188 us; speedup 1.0000x reference)
//
#include <hip/hip_runtime.h>

#define N_SEQ 4096
#define N_FFT 8192
#define LAYERS 3
#define FT 512                 // threads per FFT block

// LDS layout for conv: interleaved float2, +2 float2 pad per 32 -> all wave-local
// pass strides verified conflict-free (4 or 8 accesses/bank = minimum).
#define IDX2(i) ((i) + (((i) >> 5) << 1))

// Wave-local "barrier": DS ops from one wave complete in order; waitcnt ensures the
// wave's own writes are visible to its own subsequent reads. memory clobber fences
// the compiler; wave_barrier pins scheduling.
#define WSYNC() { asm volatile("s_waitcnt lgkmcnt(0)" ::: "memory"); __builtin_amdgcn_wave_barrier(); }

__device__ __forceinline__ float2 cmulf(float2 a, float2 b) {
    return make_float2(fmaf(a.x, b.x, -a.y * b.y), fmaf(a.x, b.y, a.y * b.x));
}
__device__ __forceinline__ float2 cmulcf(float2 a, float2 b) {   // a * conj(b)
    return make_float2(fmaf(a.x, b.x, a.y * b.y), fmaf(a.y, b.x, -a.x * b.y));
}
__device__ __forceinline__ float2 f2a(float2 a, float2 b) { return make_float2(a.x + b.x, a.y + b.y); }
__device__ __forceinline__ float2 f2s(float2 a, float2 b) { return make_float2(a.x - b.x, a.y - b.y); }

// T[q] = W_8192^{np*q}, q=1..7 (forward sign)
__device__ __forceinline__ void twchain(int np, float2* T)
{
    float c1, s1;
    __sincosf(-7.6699039394282061e-4f * (float)np, &s1, &c1);   // -2pi/8192
    T[1] = make_float2(c1, s1);
    T[2] = cmulf(T[1], T[1]);
    T[3] = cmulf(T[2], T[1]);
    T[4] = cmulf(T[2], T[2]);
    T[5] = cmulf(T[3], T[2]);
    T[6] = cmulf(T[3], T[3]);
    T[7] = cmulf(T[4], T[3]);
}

// radix-8 DIF first stage, REAL input x[0..7] = a[n' + 1024 p], twiddled by W^{n' q}
__device__ __forceinline__ void ahead8(const float* x, int np, float2* X)
{
    const float R2 = 0.70710678118654752f;
    float p0 = x[0] + x[4], q0 = x[0] - x[4];
    float p1 = x[2] + x[6], q1 = x[2] - x[6];
    float r0 = x[1] + x[5], t0 = x[1] - x[5];
    float r1 = x[3] + x[7], t1 = x[3] - x[7];
    float e0 = p0 + p1, e2 = p0 - p1;
    float o0 = r0 + r1, o2 = r0 - r1;
    float rm = R2 * (t0 - t1), rp = R2 * (t0 + t1);
    X[0] = make_float2(e0 + o0, 0.f);
    X[4] = make_float2(e0 - o0, 0.f);
    X[2] = make_float2(e2, -o2);
    X[6] = make_float2(e2,  o2);
    X[1] = make_float2(q0 + rm, -q1 - rp);
    X[5] = make_float2(q0 - rm, -q1 + rp);
    X[3] = make_float2(q0 - rm,  q1 - rp);
    X[7] = make_float2(q0 + rm,  q1 + rp);
    float2 T[8];
    twchain(np, T);
#pragma unroll
    for (int q = 1; q < 8; ++q) X[q] = cmulf(X[q], T[q]);
}

// radix-8 DIF first stage, complex input z[0..3], z[4..7] = 0 (zero padding)
__device__ __forceinline__ void zhead8(const float2* z, int np, float2* X)
{
    const float R2 = 0.70710678118654752f;
    float2 A0 = f2a(z[0], z[2]);
    float2 A2 = f2s(z[0], z[2]);
    float2 A1 = make_float2(z[0].x + z[2].y, z[0].y - z[2].x);   // z0 - i z2
    float2 A3 = make_float2(z[0].x - z[2].y, z[0].y + z[2].x);   // z0 + i z2
    float2 B0 = f2a(z[1], z[3]);
    float2 bm = f2s(z[1], z[3]);
    float2 B2 = make_float2(bm.y, -bm.x);                        // -i (z1 - z3)
    float2 u1 = make_float2(z[1].x + z[3].y, z[1].y - z[3].x);   // z1 - i z3
    float2 B1 = make_float2(R2 * (u1.x + u1.y), R2 * (u1.y - u1.x));      // W8 * u1
    float2 u3 = make_float2(z[1].x - z[3].y, z[1].y + z[3].x);   // z1 + i z3
    float2 B3 = make_float2(R2 * (u3.y - u3.x), -R2 * (u3.x + u3.y));     // W8^3 * u3
    X[0] = f2a(A0, B0); X[4] = f2s(A0, B0);
    X[1] = f2a(A1, B1); X[5] = f2s(A1, B1);
    X[2] = f2a(A2, B2); X[6] = f2s(A2, B2);
    X[3] = f2a(A3, B3); X[7] = f2s(A3, B3);
    float2 T[8];
    twchain(np, T);
#pragma unroll
    for (int q = 1; q < 8; ++q) X[q] = cmulf(X[q], T[q]);
}

// inverse radix-8 last stage, conj-twiddled, only outputs p=0..3 (n < 4096 kept)
__device__ __forceinline__ void ihead8(const float2* v, int np, float2* u)
{
    const float R2 = 0.70710678118654752f;
    float2 T[8];
    twchain(np, T);
    float2 V[8];
    V[0] = v[0];
#pragma unroll
    for (int q = 1; q < 8; ++q) V[q] = cmulcf(v[q], T[q]);
    float2 s0 = f2a(V[0], V[4]), d0 = f2s(V[0], V[4]);
    float2 s1 = f2a(V[1], V[5]), d1 = f2s(V[1], V[5]);
    float2 s2 = f2a(V[2], V[6]), d2 = f2s(V[2], V[6]);
    float2 s3 = f2a(V[3], V[7]), d3 = f2s(V[3], V[7]);
    u[0] = f2a(f2a(s0, s1), f2a(s2, s3));
    u[2] = make_float2((s0.x - s2.x) - (s1.y - s3.y),
                       (s0.y - s2.y) + (s1.x - s3.x));
    float m1 = R2 * (d1.x - d1.y), p1 = R2 * (d1.x + d1.y);
    float m3 = R2 * (d3.x - d3.y), p3 = R2 * (d3.x + d3.y);
    u[1] = make_float2(d0.x + m1 - d2.y - p3, d0.y + p1 + d2.x + m3);
    u[3] = make_float2(d0.x - p1 + d2.y + m3, d0.y + m1 - d2.x + p3);
}

// final DIF stage: 4-point DFT on contiguous quads (no twiddles), in regs
__device__ __forceinline__ void tail4_fwd(float2* y)
{
#pragma unroll
    for (int g = 0; g < 16; g += 4) {
        float2 a = f2a(y[g],     y[g + 2]);
        float2 b = f2s(y[g],     y[g + 2]);
        float2 c = f2a(y[g + 1], y[g + 3]);
        float2 w = f2s(y[g + 1], y[g + 3]);
        float2 d = make_float2(w.y, -w.x);       // -i (y1 - y3)
        y[g]     = f2a(a, c);
        y[g + 1] = f2a(b, d);
        y[g + 2] = f2s(a, c);
        y[g + 3] = f2s(b, d);
    }
}
__device__ __forceinline__ void tail4_inv(float2* y)
{
#pragma unroll
    for (int g = 0; g < 16; g += 4) {
        float2 a = f2a(y[g],     y[g + 2]);
        float2 b = f2s(y[g],     y[g + 2]);
        float2 c = f2a(y[g + 1], y[g + 3]);
        float2 d = f2s(y[g + 1], y[g + 3]);
        float2 id = make_float2(-d.y, d.x);      // i (X1 - X3)
        y[g]     = f2a(a, c);
        y[g + 2] = f2s(a, c);
        y[g + 1] = f2a(b, id);
        y[g + 3] = f2s(b, id);
    }
}

// ===== wave-local radix-16 pass (two DIF stages), float2 LDS, chunk-local =====
template<int M>
__device__ __forceinline__ void wpass16_fwd(float2* buf, int C, int lane)
{
    const int Q = M >> 4;
    const int j = lane & (Q - 1);
    const int base = C + (lane / Q) * M + j;
    const float KR[4] = {1.f, 0.9238795325f, 0.7071067812f, 0.3826834324f};
    const float KI[4] = {0.f, -0.3826834324f, -0.7071067812f, -0.9238795325f};
    float xr[4][4], xi[4][4];
#pragma unroll
    for (int a = 0; a < 4; ++a)
#pragma unroll
        for (int b = 0; b < 4; ++b) {
            float2 v = buf[IDX2(base + a * (M >> 2) + b * Q)];
            xr[a][b] = v.x; xi[a][b] = v.y;
        }
    float cj, sj;
    __sincosf(-6.283185307179586f / (float)M * (float)j, &sj, &cj);
#pragma unroll
    for (int b = 0; b < 4; ++b) {
        float c1 = cj * KR[b] - sj * KI[b];
        float s1 = cj * KI[b] + sj * KR[b];
        float c2 = c1 * c1 - s1 * s1, s2 = 2.f * c1 * s1;
        float c3 = c2 * c1 - s2 * s1, s3 = c2 * s1 + s2 * c1;
        float ar = xr[0][b] + xr[2][b], ai = xi[0][b] + xi[2][b];
        float br = xr[0][b] - xr[2][b], bi = xi[0][b] - xi[2][b];
        float cr = xr[1][b] + xr[3][b], ci = xi[1][b] + xi[3][b];
        float dr = xi[1][b] - xi[3][b], di = -(xr[1][b] - xr[3][b]);
        xr[0][b] = ar + cr;               xi[0][b] = ai + ci;
        float t1r = br + dr, t1i = bi + di;
        xr[1][b] = t1r * c1 - t1i * s1;   xi[1][b] = t1r * s1 + t1i * c1;
        float t2r = ar - cr, t2i = ai - ci;
        xr[2][b] = t2r * c2 - t2i * s2;   xi[2][b] = t2r * s2 + t2i * c2;
        float t3r = br - dr, t3i = bi - di;
        xr[3][b] = t3r * c3 - t3i * s3;   xi[3][b] = t3r * s3 + t3i * c3;
    }
    {
        float e1c = cj * cj - sj * sj, e1s = 2.f * cj * sj;      // W^{2j}
        float c1 = e1c * e1c - e1s * e1s, s1 = 2.f * e1c * e1s;  // W^{4j}
        float c2 = c1 * c1 - s1 * s1, s2 = 2.f * c1 * s1;
        float c3 = c2 * c1 - s2 * s1, s3 = c2 * s1 + s2 * c1;
#pragma unroll
        for (int a = 0; a < 4; ++a) {
            float ar = xr[a][0] + xr[a][2], ai = xi[a][0] + xi[a][2];
            float br = xr[a][0] - xr[a][2], bi = xi[a][0] - xi[a][2];
            float cr = xr[a][1] + xr[a][3], ci = xi[a][1] + xi[a][3];
            float dr = xi[a][1] - xi[a][3], di = -(xr[a][1] - xr[a][3]);
            xr[a][0] = ar + cr;               xi[a][0] = ai + ci;
            float t1r = br + dr, t1i = bi + di;
            xr[a][1] = t1r * c1 - t1i * s1;   xi[a][1] = t1r * s1 + t1i * c1;
            float t2r = ar - cr, t2i = ai - ci;
            xr[a][2] = t2r * c2 - t2i * s2;   xi[a][2] = t2r * s2 + t2i * c2;
            float t3r = br - dr, t3i = bi - di;
            xr[a][3] = t3r * c3 - t3i * s3;   xi[a][3] = t3r * s3 + t3i * c3;
        }
    }
#pragma unroll
    for (int a = 0; a < 4; ++a)
#pragma unroll
        for (int b = 0; b < 4; ++b)
            buf[IDX2(base + a * (M >> 2) + b * Q)] = make_float2(xr[a][b], xi[a][b]);
}

template<int M>
__device__ __forceinline__ void wpass16_inv(float2* buf, int C, int lane)
{
    const int Q = M >> 4;
    const int j = lane & (Q - 1);
    const int base = C + (lane / Q) * M + j;
    const float KR[4] = {1.f, 0.9238795325f, 0.7071067812f, 0.3826834324f};
    const float KI[4] = {0.f, 0.3826834324f, 0.7071067812f, 0.9238795325f};   // conj
    float xr[4][4], xi[4][4];
#pragma unroll
    for (int a = 0; a < 4; ++a)
#pragma unroll
        for (int b = 0; b < 4; ++b) {
            float2 v = buf[IDX2(base + a * (M >> 2) + b * Q)];
            xr[a][b] = v.x; xi[a][b] = v.y;
        }
    float cj, sj;
    __sincosf(6.283185307179586f / (float)M * (float)j, &sj, &cj);
    {
        float e1c = cj * cj - sj * sj, e1s = 2.f * cj * sj;
        float c1 = e1c * e1c - e1s * e1s, s1 = 2.f * e1c * e1s;
        float c2 = c1 * c1 - s1 * s1, s2 = 2.f * c1 * s1;
        float c3 = c2 * c1 - s2 * s1, s3 = c2 * s1 + s2 * c1;
#pragma unroll
        for (int a = 0; a < 4; ++a) {
            float t0r = xr[a][0], t0i = xi[a][0];
            float t1r = xr[a][1] * c1 - xi[a][1] * s1, t1i = xr[a][1] * s1 + xi[a][1] * c1;
            float t2r = xr[a][2] * c2 - xi[a][2] * s2, t2i = xr[a][2] * s2 + xi[a][2] * c2;
            float t3r = xr[a][3] * c3 - xi[a][3] * s3, t3i = xr[a][3] * s3 + xi[a][3] * c3;
            float pr = t0r + t2r, pi = t0i + t2i;
            float qr = t0r - t2r, qi = t0i - t2i;
            float rr = t1r + t3r, ri = t1i + t3i;
            float sr = -(t1i - t3i), si = t1r - t3r;
            xr[a][0] = pr + rr; xi[a][0] = pi + ri;
            xr[a][1] = qr + sr; xi[a][1] = qi + si;
            xr[a][2] = pr - rr; xi[a][2] = pi - ri;
            xr[a][3] = qr - sr; xi[a][3] = qi - si;
        }
    }
#pragma unroll
    for (int b = 0; b < 4; ++b) {
        float c1 = cj * KR[b] - sj * KI[b];
        float s1 = cj * KI[b] + sj * KR[b];
        float c2 = c1 * c1 - s1 * s1, s2 = 2.f * c1 * s1;
        float c3 = c2 * c1 - s2 * s1, s3 = c2 * s1 + s2 * c1;
        float t0r = xr[0][b], t0i = xi[0][b];
        float t1r = xr[1][b] * c1 - xi[1][b] * s1, t1i = xr[1][b] * s1 + xi[1][b] * c1;
        float t2r = xr[2][b] * c2 - xi[2][b] * s2, t2i = xr[2][b] * s2 + xi[2][b] * c2;
        float t3r = xr[3][b] * c3 - xi[3][b] * s3, t3i = xr[3][b] * s3 + xi[3][b] * c3;
        float pr = t0r + t2r, pi = t0i + t2i;
        float qr = t0r - t2r, qi = t0i - t2i;
        float rr = t1r + t3r, ri = t1i + t3i;
        float sr = -(t1i - t3i), si = t1r - t3r;
        xr[0][b] = pr + rr; xi[0][b] = pi + ri;
        xr[1][b] = qr + sr; xi[1][b] = qi + si;
        xr[2][b] = pr - rr; xi[2][b] = pi - ri;
        xr[3][b] = qr - sr; xi[3][b] = qi - si;
    }
#pragma unroll
    for (int a = 0; a < 4; ++a)
#pragma unroll
        for (int b = 0; b < 4; ++b)
            buf[IDX2(base + a * (M >> 2) + b * Q)] = make_float2(xr[a][b], xi[a][b]);
}

// ============ prep: [blocks 0..255] RPE (32 pos/block, all 512 outputs) -> a_t
//              [blocks 256..767] transpose x -> xt2 ============
__global__ __launch_bounds__(512, 2) void prep_kernel(
    const float* __restrict__ x,
    const float* __restrict__ w_in, const float* __restrict__ b_in,
    const float* __restrict__ w_hid, const float* __restrict__ b_hid,
    const float* __restrict__ w_out, const float* __restrict__ b_out,
    float* __restrict__ a_t, float2* __restrict__ xt2)
{
    __shared__ __align__(16) char smem[43264];
    const int tid = threadIdx.x;

    if (blockIdx.x >= 256) {
        // ---- transpose x: (2,8,N,64) -> xt2[hd][n] = (x_b0, x_b1) ----
        float (*t0)[65] = (float (*)[65])smem;
        float (*t1)[65] = (float (*)[65])(smem + 16640);
        int bb = blockIdx.x - 256;
        int h = bb >> 6;
        int nb = bb & 63;
        int lx = tid & 63;
        int ly = tid >> 6;          // 0..7
        const float* s0 = x + ((size_t)h * N_SEQ + nb * 64) * 64;
        const float* s1 = x + ((size_t)(8 + h) * N_SEQ + nb * 64) * 64;
        for (int r = ly; r < 64; r += 8) {
            t0[r][lx] = s0[r * 64 + lx];
            t1[r][lx] = s1[r * 64 + lx];
        }
        __syncthreads();
        for (int r = ly; r < 64; r += 8) {
            float2* dst = xt2 + (size_t)(h * 64 + r) * N_SEQ + nb * 64;
            dst[lx] = make_float2(t0[lx][r], t1[lx][r]);
        }
        return;
    }

    float (*ubuf)[65] = (float (*)[65])smem;               // [pos][feat]
    float (*sums)[17] = (float (*)[17])(smem + 8320);
    float4* wl        = (float4*)(smem + 10496);           // weight area

    // ---- hidden chain: thread = (p = tid&31, s = tid>>5 feature-quad) ----
    {
        const int p = tid & 31;
        const int s = tid >> 5;       // 0..15, features s*4..s*4+3
        const int pos = blockIdx.x * 32 + p;
        float v;
        if (pos == 0 || pos == N_SEQ) v = 1.0f;
        else if (pos < N_SEQ)         v = 1.0f / (float)(pos + 1);
        else                          v = -1.0f / (float)(2 * N_SEQ + 1 - pos);

        float h[4];
#pragma unroll
        for (int i = 0; i < 4; ++i) {
            int f = s * 4 + i;
            h[i] = v * w_in[f] + b_in[f];
        }
        for (int L = 0; L < LAYERS; ++L) {
            const float4* wsrc = (const float4*)(w_hid + L * 4096);
            wl[tid] = wsrc[tid];
            wl[tid + 512] = wsrc[tid + 512];
            float s2 = h[0]*h[0] + h[1]*h[1] + h[2]*h[2] + h[3]*h[3];
            sums[p][s] = s2;
            __syncthreads();
            float tot = 0.f;
#pragma unroll
            for (int g = 0; g < 16; ++g) tot += sums[p][g];
            float r = rsqrtf(tot * (1.f / 64.f) + 1e-8f);
#pragma unroll
            for (int i = 0; i < 4; ++i)
                ubuf[p][s * 4 + i] = fmaxf(h[i] * r, 0.f);
            __syncthreads();           // ubuf + wl ready
            float acc[4];
#pragma unroll
            for (int i = 0; i < 4; ++i) acc[i] = b_hid[L * 64 + s * 4 + i];
#pragma unroll 8
            for (int j = 0; j < 64; ++j) {
                float uj = ubuf[p][j];
                float4 w = wl[j * 16 + s];
                acc[0] = fmaf(uj, w.x, acc[0]); acc[1] = fmaf(uj, w.y, acc[1]);
                acc[2] = fmaf(uj, w.z, acc[2]); acc[3] = fmaf(uj, w.w, acc[3]);
            }
#pragma unroll
            for (int i = 0; i < 4; ++i) h[i] = acc[i];
            __syncthreads();           // before wl/sums/ubuf overwrite
        }
        // final RMS + relu -> ubuf
        float s2 = h[0]*h[0] + h[1]*h[1] + h[2]*h[2] + h[3]*h[3];
        sums[p][s] = s2;
        __syncthreads();
        float tot = 0.f;
#pragma unroll
        for (int g = 0; g < 16; ++g) tot += sums[p][g];
        float r = rsqrtf(tot * (1.f / 64.f) + 1e-8f);
#pragma unroll
        for (int i = 0; i < 4; ++i)
            ubuf[p][s * 4 + i] = fmaxf(h[i] * r, 0.f);
        __syncthreads();
    }

    // ---- out GEMM: thread = (o = tid>>3 octet, pg = tid&7 pos-group of 4) ----
    {
        const int o  = tid >> 3;
        const int pg = tid & 7;
        const int pos0 = blockIdx.x * 32;
        float4* wt = wl;               // [16][128] float4: row jj = 128 float4
        float acc[8][4];
#pragma unroll
        for (int ii = 0; ii < 8; ++ii) {
            float bo = b_out[o * 8 + ii];
#pragma unroll
            for (int i = 0; i < 4; ++i) acc[ii][i] = bo;
        }
        for (int jc = 0; jc < 4; ++jc) {
            float4 wreg[4];
#pragma unroll
            for (int k = 0; k < 4; ++k) {
                int i4 = k * 512 + tid;           // 0..2047
                int jj = i4 >> 7, f4 = i4 & 127;
                wreg[k] = *(const float4*)(w_out + (jc * 16 + jj) * 512 + f4 * 4);
            }
            __syncthreads();           // prior wt reads done (1st iter: hidden's wl)
#pragma unroll
            for (int k = 0; k < 4; ++k) {
                int i4 = k * 512 + tid;
                wt[i4] = wreg[k];
            }
            __syncthreads();
#pragma unroll
            for (int jj = 0; jj < 16; ++jj) {
                int j = jc * 16 + jj;
                float4 w0 = wt[jj * 128 + o * 2];
                float4 w1 = wt[jj * 128 + o * 2 + 1];
                float u0 = ubuf[pg * 4 + 0][j];
                float u1 = ubuf[pg * 4 + 1][j];
                float u2 = ubuf[pg * 4 + 2][j];
                float u3 = ubuf[pg * 4 + 3][j];
                acc[0][0] = fmaf(u0, w0.x, acc[0][0]); acc[0][1] = fmaf(u1, w0.x, acc[0][1]);
                acc[0][2] = fmaf(u2, w0.x, acc[0][2]); acc[0][3] = fmaf(u3, w0.x, acc[0][3]);
                acc[1][0] = fmaf(u0, w0.y, acc[1][0]); acc[1][1] = fmaf(u1, w0.y, acc[1][1]);
                acc[1][2] = fmaf(u2, w0.y, acc[1][2]); acc[1][3] = fmaf(u3, w0.y, acc[1][3]);
                acc[2][0] = fmaf(u0, w0.z, acc[2][0]); acc[2][1] = fmaf(u1, w0.z, acc[2][1]);
                acc[2][2] = fmaf(u2, w0.z, acc[2][2]); acc[2][3] = fmaf(u3, w0.z, acc[2][3]);
                acc[3][0] = fmaf(u0, w0.w, acc[3][0]); acc[3][1] = fmaf(u1, w0.w, acc[3][1]);
                acc[3][2] = fmaf(u2, w0.w, acc[3][2]); acc[3][3] = fmaf(u3, w0.w, acc[3][3]);
                acc[4][0] = fmaf(u0, w1.x, acc[4][0]); acc[4][1] = fmaf(u1, w1.x, acc[4][1]);
                acc[4][2] = fmaf(u2, w1.x, acc[4][2]); acc[4][3] = fmaf(u3, w1.x, acc[4][3]);
                acc[5][0] = fmaf(u0, w1.y, acc[5][0]); acc[5][1] = fmaf(u1, w1.y, acc[5][1]);
                acc[5][2] = fmaf(u2, w1.y, acc[5][2]); acc[5][3] = fmaf(u3, w1.y, acc[5][3]);
                acc[6][0] = fmaf(u0, w1.z, acc[6][0]); acc[6][1] = fmaf(u1, w1.z, acc[6][1]);
                acc[6][2] = fmaf(u2, w1.z, acc[6][2]); acc[6][3] = fmaf(u3, w1.z, acc[6][3]);
                acc[7][0] = fmaf(u0, w1.w, acc[7][0]); acc[7][1] = fmaf(u1, w1.w, acc[7][1]);
                acc[7][2] = fmaf(u2, w1.w, acc[7][2]); acc[7][3] = fmaf(u3, w1.w, acc[7][3]);
            }
            __syncthreads();           // wt reads done before next stage
        }
#pragma unroll
        for (int ii = 0; ii < 8; ++ii) {
            int f = o * 8 + ii;
#pragma unroll
            for (int i = 0; i < 4; ++i)
                a_t[(size_t)f * N_FFT + pos0 + pg * 4 + i] = acc[ii][i];
        }
    }
}

// ========== conv: wave-local FFT decomposition (see round-2 notes).
// *** ROUND-5 PROBE ***: body executed TWICE per dispatch (idempotent: pure
// function of a_t/xt2 -> out_t2). Purpose: (a) dur_us - baseline = conv's true
// cost; (b) doubled dispatch exceeds the 45us fill => conv's own rocprof
// counters become visible in top-5. Remove the rep loop next round. ==========
__global__ __launch_bounds__(FT, 2) void conv_kernel(const float* __restrict__ a_t,
                                                     const float2* __restrict__ xt2,
                                                     float2* __restrict__ out_t2)
{
    __shared__ __align__(16) float2 buf[8704];   // 8192 + 2 per 32 pad = 69632 B
    const int tid = threadIdx.x;
    const int lane = tid & 63;
    const int C = (tid >> 6) << 10;              // wave chunk base (1024 elems)
    const int hd = blockIdx.x;

    for (int rep = 0; rep < 2; ++rep) {
    // ---- A forward head: radix-8 DIF stage fused with global read (real) ----
    {
        const float2* asrc = (const float2*)(a_t + (size_t)hd * N_FFT);
        float2 av[8];
#pragma unroll
        for (int p = 0; p < 8; ++p) av[p] = asrc[tid + 512 * p];
        float xa[8], xb[8];
#pragma unroll
        for (int p = 0; p < 8; ++p) { xa[p] = av[p].x; xb[p] = av[p].y; }
        float2 X0[8], X1[8];
        ahead8(xa, 2 * tid,     X0);
        ahead8(xb, 2 * tid + 1, X1);
#pragma unroll
        for (int q = 0; q < 8; ++q)
            *(float4*)&buf[IDX2(q * 1024 + 2 * tid)] =
                make_float4(X0[q].x, X0[q].y, X1[q].x, X1[q].y);
    }
    __syncthreads();
    wpass16_fwd<1024>(buf, C, lane);
    WSYNC();
    wpass16_fwd<64>(buf, C, lane);
    WSYNC();
    // ---- A tail: spectrum into registers (1/N folded in later) ----
    float2 asp[16];
#pragma unroll
    for (int k = 0; k < 8; ++k) {
        float4 v = *(const float4*)&buf[IDX2(C + 16 * lane + 2 * k)];
        asp[2 * k]     = make_float2(v.x, v.y);
        asp[2 * k + 1] = make_float2(v.z, v.w);
    }
    tail4_fwd(asp);
    // prefetch z (global) before the barrier so HBM latency hides under it
    float4 zl[4];
    {
        const float4* zsrc = (const float4*)(xt2 + (size_t)hd * N_SEQ);
#pragma unroll
        for (int p = 0; p < 4; ++p) zl[p] = zsrc[tid + 512 * p];
    }
    __syncthreads();                 // all A-tail LDS reads done before overwrite
    // ---- Z forward head: radix-8 with upper half zero (zero padding) ----
    {
        float2 z0[4], z1[4];
#pragma unroll
        for (int p = 0; p < 4; ++p) {
            z0[p] = make_float2(zl[p].x, zl[p].y);
            z1[p] = make_float2(zl[p].z, zl[p].w);
        }
        float2 X0[8], X1[8];
        zhead8(z0, 2 * tid,     X0);
        zhead8(z1, 2 * tid + 1, X1);
#pragma unroll
        for (int q = 0; q < 8; ++q)
            *(float4*)&buf[IDX2(q * 1024 + 2 * tid)] =
                make_float4(X0[q].x, X0[q].y, X1[q].x, X1[q].y);
    }
    __syncthreads();
    wpass16_fwd<1024>(buf, C, lane);
    WSYNC();
    wpass16_fwd<64>(buf, C, lane);
    WSYNC();
    // ---- Z tail + pointwise (A in regs, 1/N fused) + inverse tail ----
    {
        float2 zp[16];
#pragma unroll
        for (int k = 0; k < 8; ++k) {
            float4 v = *(const float4*)&buf[IDX2(C + 16 * lane + 2 * k)];
            zp[2 * k]     = make_float2(v.x, v.y);
            zp[2 * k + 1] = make_float2(v.z, v.w);
        }
        tail4_fwd(zp);
        const float inv = 1.0f / (float)N_FFT;
#pragma unroll
        for (int c = 0; c < 16; ++c) {
            float2 m = cmulf(zp[c], asp[c]);
            zp[c] = make_float2(m.x * inv, m.y * inv);
        }
        tail4_inv(zp);
#pragma unroll
        for (int k = 0; k < 8; ++k)
            *(float4*)&buf[IDX2(C + 16 * lane + 2 * k)] =
                make_float4(zp[2 * k].x, zp[2 * k].y, zp[2 * k + 1].x, zp[2 * k + 1].y);
    }
    WSYNC();
    wpass16_inv<64>(buf, C, lane);
    WSYNC();
    wpass16_inv<1024>(buf, C, lane);
    __syncthreads();
    // ---- inverse head: conj-twiddled half-output radix-8, store [0,4096) ----
    {
        float2 v0[8], v1[8];
#pragma unroll
        for (int q = 0; q < 8; ++q) {
            float4 r = *(const float4*)&buf[IDX2(q * 1024 + 2 * tid)];
            v0[q] = make_float2(r.x, r.y);
            v1[q] = make_float2(r.z, r.w);
        }
        float2 u0[4], u1[4];
        ihead8(v0, 2 * tid,     u0);
        ihead8(v1, 2 * tid + 1, u1);
        float4* dst = (float4*)(out_t2 + (size_t)hd * N_SEQ);
#pragma unroll
        for (int p = 0; p < 4; ++p)
            dst[tid + 512 * p] = make_float4(u0[p].x, u0[p].y, u1[p].x, u1[p].y);
    }
    __syncthreads();               // rep-1 final LDS reads done before rep-2 head writes
    }
}

// ========== transpose out: out_t2[hd][n] -> out (2,8,N,64) ==========
__global__ __launch_bounds__(256) void transpose_o_kernel(const float2* __restrict__ out_t2,
                                                          float* __restrict__ out)
{
    __shared__ float t0[64][65];
    __shared__ float t1[64][65];
    int h = blockIdx.x >> 6;
    int nb = blockIdx.x & 63;
    int lx = threadIdx.x & 63;
    int ly = threadIdx.x >> 6;
    for (int r = ly; r < 64; r += 4) {
        float2 v = out_t2[(size_t)(h * 64 + r) * N_SEQ + nb * 64 + lx];
        t0[r][lx] = v.x;
        t1[r][lx] = v.y;
    }
    __syncthreads();
    float* d0 = out + ((size_t)h * N_SEQ + nb * 64) * 64;
    float* d1 = out + ((size_t)(8 + h) * N_SEQ + nb * 64) * 64;
    for (int r = ly; r < 64; r += 4) {
        d0[r * 64 + lx] = t0[lx][r];
        d1[r * 64 + lx] = t1[lx][r];
    }
}

extern "C" void kernel_launch(void* const* d_in, const int* in_sizes, int n_in,
                              void* d_out, int out_size, void* d_ws, size_t ws_size,
                              hipStream_t stream)
{
    const float* x     = (const float*)d_in[0];
    const float* w_in  = (const float*)d_in[1];
    const float* b_in  = (const float*)d_in[2];
    const float* w_hid = (const float*)d_in[3];
    const float* b_hid = (const float*)d_in[4];
    const float* w_out = (const float*)d_in[5];
    const float* b_out = (const float*)d_in[6];
    float* out = (float*)d_out;

    char* ws = (char*)d_ws;
    float2* xt2    = (float2*)ws;                               // 16 MB
    float*  a_t    = (float*)(ws + (size_t)16 * 1024 * 1024);   // 16 MB
    float2* out_t2 = (float2*)(ws + (size_t)32 * 1024 * 1024);  // 16 MB

    prep_kernel<<<768, 512, 0, stream>>>(x, w_in, b_in, w_hid, b_hid, w_out, b_out,
                                         a_t, xt2);
    conv_kernel<<<512, FT, 0, stream>>>(a_t, xt2, out_t2);
    transpose_o_kernel<<<512, 256, 0, stream>>>(out_t2, out);
}

// Round 6
// 151.367 us; speedup vs baseline: 1.9832x; 1.9832x over previous
//
#include <hip/hip_runtime.h>

#define N_SEQ 4096
#define N_FFT 8192
#define LAYERS 3
#define FT 512                 // threads per FFT block

// LDS layout for conv: interleaved float2, +2 float2 pad per 32 -> all wave-local
// pass strides verified conflict-free (4 or 8 accesses/bank = minimum).
#define IDX2(i) ((i) + (((i) >> 5) << 1))

// Wave-local "barrier": DS ops from one wave complete in order; waitcnt ensures the
// wave's own writes are visible to its own subsequent reads.
#define WSYNC() { asm volatile("s_waitcnt lgkmcnt(0)" ::: "memory"); __builtin_amdgcn_wave_barrier(); }

// ===== SESSION LEDGER (counters, MI355X) =====
// R1: conv launch_bounds(512,4) -> VGPR cap 64 -> 300MB scratch, conv 98us. Fix: (512,2).
// R5 probe: conv x2 reps = 270us, VGPR=128 (cap), FETCH+WRITE 670MB vs 100MB algo
//   -> conv spills ~285MB/rep AT THE 128 CAP (asp[16]+zl[4] live across Z-FFT).
//   dur_us excludes the 45us harness fill; prep+transpose+gaps = 300-270 = 30us.
//   => conv-without-rep was ~120us in R2/R3 (hidden from top-5 by NaN-row drops).
// R6: split conv -> afft + zconv so no array lives across an FFT phase.

__device__ __forceinline__ float2 cmulf(float2 a, float2 b) {
    return make_float2(fmaf(a.x, b.x, -a.y * b.y), fmaf(a.x, b.y, a.y * b.x));
}
__device__ __forceinline__ float2 cmulcf(float2 a, float2 b) {   // a * conj(b)
    return make_float2(fmaf(a.x, b.x, a.y * b.y), fmaf(a.y, b.x, -a.x * b.y));
}
__device__ __forceinline__ float2 f2a(float2 a, float2 b) { return make_float2(a.x + b.x, a.y + b.y); }
__device__ __forceinline__ float2 f2s(float2 a, float2 b) { return make_float2(a.x - b.x, a.y - b.y); }

// T[q] = W_8192^{np*q}, q=1..7 (forward sign)
__device__ __forceinline__ void twchain(int np, float2* T)
{
    float c1, s1;
    __sincosf(-7.6699039394282061e-4f * (float)np, &s1, &c1);   // -2pi/8192
    T[1] = make_float2(c1, s1);
    T[2] = cmulf(T[1], T[1]);
    T[3] = cmulf(T[2], T[1]);
    T[4] = cmulf(T[2], T[2]);
    T[5] = cmulf(T[3], T[2]);
    T[6] = cmulf(T[3], T[3]);
    T[7] = cmulf(T[4], T[3]);
}

// radix-8 DIF first stage, REAL input x[0..7] = a[n' + 1024 p], twiddled by W^{n' q}
__device__ __forceinline__ void ahead8(const float* x, int np, float2* X)
{
    const float R2 = 0.70710678118654752f;
    float p0 = x[0] + x[4], q0 = x[0] - x[4];
    float p1 = x[2] + x[6], q1 = x[2] - x[6];
    float r0 = x[1] + x[5], t0 = x[1] - x[5];
    float r1 = x[3] + x[7], t1 = x[3] - x[7];
    float e0 = p0 + p1, e2 = p0 - p1;
    float o0 = r0 + r1, o2 = r0 - r1;
    float rm = R2 * (t0 - t1), rp = R2 * (t0 + t1);
    X[0] = make_float2(e0 + o0, 0.f);
    X[4] = make_float2(e0 - o0, 0.f);
    X[2] = make_float2(e2, -o2);
    X[6] = make_float2(e2,  o2);
    X[1] = make_float2(q0 + rm, -q1 - rp);
    X[5] = make_float2(q0 - rm, -q1 + rp);
    X[3] = make_float2(q0 - rm,  q1 - rp);
    X[7] = make_float2(q0 + rm,  q1 + rp);
    float2 T[8];
    twchain(np, T);
#pragma unroll
    for (int q = 1; q < 8; ++q) X[q] = cmulf(X[q], T[q]);
}

// radix-8 DIF first stage, complex input z[0..3], z[4..7] = 0 (zero padding)
__device__ __forceinline__ void zhead8(const float2* z, int np, float2* X)
{
    const float R2 = 0.70710678118654752f;
    float2 A0 = f2a(z[0], z[2]);
    float2 A2 = f2s(z[0], z[2]);
    float2 A1 = make_float2(z[0].x + z[2].y, z[0].y - z[2].x);   // z0 - i z2
    float2 A3 = make_float2(z[0].x - z[2].y, z[0].y + z[2].x);   // z0 + i z2
    float2 B0 = f2a(z[1], z[3]);
    float2 bm = f2s(z[1], z[3]);
    float2 B2 = make_float2(bm.y, -bm.x);                        // -i (z1 - z3)
    float2 u1 = make_float2(z[1].x + z[3].y, z[1].y - z[3].x);   // z1 - i z3
    float2 B1 = make_float2(R2 * (u1.x + u1.y), R2 * (u1.y - u1.x));      // W8 * u1
    float2 u3 = make_float2(z[1].x - z[3].y, z[1].y + z[3].x);   // z1 + i z3
    float2 B3 = make_float2(R2 * (u3.y - u3.x), -R2 * (u3.x + u3.y));     // W8^3 * u3
    X[0] = f2a(A0, B0); X[4] = f2s(A0, B0);
    X[1] = f2a(A1, B1); X[5] = f2s(A1, B1);
    X[2] = f2a(A2, B2); X[6] = f2s(A2, B2);
    X[3] = f2a(A3, B3); X[7] = f2s(A3, B3);
    float2 T[8];
    twchain(np, T);
#pragma unroll
    for (int q = 1; q < 8; ++q) X[q] = cmulf(X[q], T[q]);
}

// inverse radix-8 last stage, conj-twiddled, only outputs p=0..3 (n < 4096 kept)
__device__ __forceinline__ void ihead8(const float2* v, int np, float2* u)
{
    const float R2 = 0.70710678118654752f;
    float2 T[8];
    twchain(np, T);
    float2 V[8];
    V[0] = v[0];
#pragma unroll
    for (int q = 1; q < 8; ++q) V[q] = cmulcf(v[q], T[q]);
    float2 s0 = f2a(V[0], V[4]), d0 = f2s(V[0], V[4]);
    float2 s1 = f2a(V[1], V[5]), d1 = f2s(V[1], V[5]);
    float2 s2 = f2a(V[2], V[6]), d2 = f2s(V[2], V[6]);
    float2 s3 = f2a(V[3], V[7]), d3 = f2s(V[3], V[7]);
    u[0] = f2a(f2a(s0, s1), f2a(s2, s3));
    u[2] = make_float2((s0.x - s2.x) - (s1.y - s3.y),
                       (s0.y - s2.y) + (s1.x - s3.x));
    float m1 = R2 * (d1.x - d1.y), p1 = R2 * (d1.x + d1.y);
    float m3 = R2 * (d3.x - d3.y), p3 = R2 * (d3.x + d3.y);
    u[1] = make_float2(d0.x + m1 - d2.y - p3, d0.y + p1 + d2.x + m3);
    u[3] = make_float2(d0.x - p1 + d2.y + m3, d0.y + m1 - d2.x + p3);
}

// final DIF stage: 4-point DFT on contiguous quads (no twiddles), in regs
__device__ __forceinline__ void tail4_fwd(float2* y)
{
#pragma unroll
    for (int g = 0; g < 16; g += 4) {
        float2 a = f2a(y[g],     y[g + 2]);
        float2 b = f2s(y[g],     y[g + 2]);
        float2 c = f2a(y[g + 1], y[g + 3]);
        float2 w = f2s(y[g + 1], y[g + 3]);
        float2 d = make_float2(w.y, -w.x);       // -i (y1 - y3)
        y[g]     = f2a(a, c);
        y[g + 1] = f2a(b, d);
        y[g + 2] = f2s(a, c);
        y[g + 3] = f2s(b, d);
    }
}
__device__ __forceinline__ void tail4_inv(float2* y)
{
#pragma unroll
    for (int g = 0; g < 16; g += 4) {
        float2 a = f2a(y[g],     y[g + 2]);
        float2 b = f2s(y[g],     y[g + 2]);
        float2 c = f2a(y[g + 1], y[g + 3]);
        float2 d = f2s(y[g + 1], y[g + 3]);
        float2 id = make_float2(-d.y, d.x);      // i (X1 - X3)
        y[g]     = f2a(a, c);
        y[g + 2] = f2s(a, c);
        y[g + 1] = f2a(b, id);
        y[g + 3] = f2s(b, id);
    }
}

// ===== wave-local radix-16 pass (two DIF stages), float2 LDS, chunk-local =====
template<int M>
__device__ __forceinline__ void wpass16_fwd(float2* buf, int C, int lane)
{
    const int Q = M >> 4;
    const int j = lane & (Q - 1);
    const int base = C + (lane / Q) * M + j;
    const float KR[4] = {1.f, 0.9238795325f, 0.7071067812f, 0.3826834324f};
    const float KI[4] = {0.f, -0.3826834324f, -0.7071067812f, -0.9238795325f};
    float xr[4][4], xi[4][4];
#pragma unroll
    for (int a = 0; a < 4; ++a)
#pragma unroll
        for (int b = 0; b < 4; ++b) {
            float2 v = buf[IDX2(base + a * (M >> 2) + b * Q)];
            xr[a][b] = v.x; xi[a][b] = v.y;
        }
    float cj, sj;
    __sincosf(-6.283185307179586f / (float)M * (float)j, &sj, &cj);
#pragma unroll
    for (int b = 0; b < 4; ++b) {
        float c1 = cj * KR[b] - sj * KI[b];
        float s1 = cj * KI[b] + sj * KR[b];
        float c2 = c1 * c1 - s1 * s1, s2 = 2.f * c1 * s1;
        float c3 = c2 * c1 - s2 * s1, s3 = c2 * s1 + s2 * c1;
        float ar = xr[0][b] + xr[2][b], ai = xi[0][b] + xi[2][b];
        float br = xr[0][b] - xr[2][b], bi = xi[0][b] - xi[2][b];
        float cr = xr[1][b] + xr[3][b], ci = xi[1][b] + xi[3][b];
        float dr = xi[1][b] - xi[3][b], di = -(xr[1][b] - xr[3][b]);
        xr[0][b] = ar + cr;               xi[0][b] = ai + ci;
        float t1r = br + dr, t1i = bi + di;
        xr[1][b] = t1r * c1 - t1i * s1;   xi[1][b] = t1r * s1 + t1i * c1;
        float t2r = ar - cr, t2i = ai - ci;
        xr[2][b] = t2r * c2 - t2i * s2;   xi[2][b] = t2r * s2 + t2i * c2;
        float t3r = br - dr, t3i = bi - di;
        xr[3][b] = t3r * c3 - t3i * s3;   xi[3][b] = t3r * s3 + t3i * c3;
    }
    {
        float e1c = cj * cj - sj * sj, e1s = 2.f * cj * sj;      // W^{2j}
        float c1 = e1c * e1c - e1s * e1s, s1 = 2.f * e1c * e1s;  // W^{4j}
        float c2 = c1 * c1 - s1 * s1, s2 = 2.f * c1 * s1;
        float c3 = c2 * c1 - s2 * s1, s3 = c2 * s1 + s2 * c1;
#pragma unroll
        for (int a = 0; a < 4; ++a) {
            float ar = xr[a][0] + xr[a][2], ai = xi[a][0] + xi[a][2];
            float br = xr[a][0] - xr[a][2], bi = xi[a][0] - xi[a][2];
            float cr = xr[a][1] + xr[a][3], ci = xi[a][1] + xi[a][3];
            float dr = xi[a][1] - xi[a][3], di = -(xr[a][1] - xr[a][3]);
            xr[a][0] = ar + cr;               xi[a][0] = ai + ci;
            float t1r = br + dr, t1i = bi + di;
            xr[a][1] = t1r * c1 - t1i * s1;   xi[a][1] = t1r * s1 + t1i * c1;
            float t2r = ar - cr, t2i = ai - ci;
            xr[a][2] = t2r * c2 - t2i * s2;   xi[a][2] = t2r * s2 + t2i * c2;
            float t3r = br - dr, t3i = bi - di;
            xr[a][3] = t3r * c3 - t3i * s3;   xi[a][3] = t3r * s3 + t3i * c3;
        }
    }
#pragma unroll
    for (int a = 0; a < 4; ++a)
#pragma unroll
        for (int b = 0; b < 4; ++b)
            buf[IDX2(base + a * (M >> 2) + b * Q)] = make_float2(xr[a][b], xi[a][b]);
}

template<int M>
__device__ __forceinline__ void wpass16_inv(float2* buf, int C, int lane)
{
    const int Q = M >> 4;
    const int j = lane & (Q - 1);
    const int base = C + (lane / Q) * M + j;
    const float KR[4] = {1.f, 0.9238795325f, 0.7071067812f, 0.3826834324f};
    const float KI[4] = {0.f, 0.3826834324f, 0.7071067812f, 0.9238795325f};   // conj
    float xr[4][4], xi[4][4];
#pragma unroll
    for (int a = 0; a < 4; ++a)
#pragma unroll
        for (int b = 0; b < 4; ++b) {
            float2 v = buf[IDX2(base + a * (M >> 2) + b * Q)];
            xr[a][b] = v.x; xi[a][b] = v.y;
        }
    float cj, sj;
    __sincosf(6.283185307179586f / (float)M * (float)j, &sj, &cj);
    {
        float e1c = cj * cj - sj * sj, e1s = 2.f * cj * sj;
        float c1 = e1c * e1c - e1s * e1s, s1 = 2.f * e1c * e1s;
        float c2 = c1 * c1 - s1 * s1, s2 = 2.f * c1 * s1;
        float c3 = c2 * c1 - s2 * s1, s3 = c2 * s1 + s2 * c1;
#pragma unroll
        for (int a = 0; a < 4; ++a) {
            float t0r = xr[a][0], t0i = xi[a][0];
            float t1r = xr[a][1] * c1 - xi[a][1] * s1, t1i = xr[a][1] * s1 + xi[a][1] * c1;
            float t2r = xr[a][2] * c2 - xi[a][2] * s2, t2i = xr[a][2] * s2 + xi[a][2] * c2;
            float t3r = xr[a][3] * c3 - xi[a][3] * s3, t3i = xr[a][3] * s3 + xi[a][3] * c3;
            float pr = t0r + t2r, pi = t0i + t2i;
            float qr = t0r - t2r, qi = t0i - t2i;
            float rr = t1r + t3r, ri = t1i + t3i;
            float sr = -(t1i - t3i), si = t1r - t3r;
            xr[a][0] = pr + rr; xi[a][0] = pi + ri;
            xr[a][1] = qr + sr; xi[a][1] = qi + si;
            xr[a][2] = pr - rr; xi[a][2] = pi - ri;
            xr[a][3] = qr - sr; xi[a][3] = qi - si;
        }
    }
#pragma unroll
    for (int b = 0; b < 4; ++b) {
        float c1 = cj * KR[b] - sj * KI[b];
        float s1 = cj * KI[b] + sj * KR[b];
        float c2 = c1 * c1 - s1 * s1, s2 = 2.f * c1 * s1;
        float c3 = c2 * c1 - s2 * s1, s3 = c2 * s1 + s2 * c1;
        float t0r = xr[0][b], t0i = xi[0][b];
        float t1r = xr[1][b] * c1 - xi[1][b] * s1, t1i = xr[1][b] * s1 + xi[1][b] * c1;
        float t2r = xr[2][b] * c2 - xi[2][b] * s2, t2i = xr[2][b] * s2 + xi[2][b] * c2;
        float t3r = xr[3][b] * c3 - xi[3][b] * s3, t3i = xr[3][b] * s3 + xi[3][b] * c3;
        float pr = t0r + t2r, pi = t0i + t2i;
        float qr = t0r - t2r, qi = t0i - t2i;
        float rr = t1r + t3r, ri = t1i + t3i;
        float sr = -(t1i - t3i), si = t1r - t3r;
        xr[0][b] = pr + rr; xi[0][b] = pi + ri;
        xr[1][b] = qr + sr; xi[1][b] = qi + si;
        xr[2][b] = pr - rr; xi[2][b] = pi - ri;
        xr[3][b] = qr - sr; xi[3][b] = qi - si;
    }
#pragma unroll
    for (int a = 0; a < 4; ++a)
#pragma unroll
        for (int b = 0; b < 4; ++b)
            buf[IDX2(base + a * (M >> 2) + b * Q)] = make_float2(xr[a][b], xi[a][b]);
}

// ============ prep: [blocks 0..255] RPE (32 pos/block, all 512 outputs) -> a_t
//              [blocks 256..767] transpose x -> xt2 ============
__global__ __launch_bounds__(512, 2) void prep_kernel(
    const float* __restrict__ x,
    const float* __restrict__ w_in, const float* __restrict__ b_in,
    const float* __restrict__ w_hid, const float* __restrict__ b_hid,
    const float* __restrict__ w_out, const float* __restrict__ b_out,
    float* __restrict__ a_t, float2* __restrict__ xt2)
{
    __shared__ __align__(16) char smem[43264];
    const int tid = threadIdx.x;

    if (blockIdx.x >= 256) {
        // ---- transpose x: (2,8,N,64) -> xt2[hd][n] = (x_b0, x_b1) ----
        float (*t0)[65] = (float (*)[65])smem;
        float (*t1)[65] = (float (*)[65])(smem + 16640);
        int bb = blockIdx.x - 256;
        int h = bb >> 6;
        int nb = bb & 63;
        int lx = tid & 63;
        int ly = tid >> 6;          // 0..7
        const float* s0 = x + ((size_t)h * N_SEQ + nb * 64) * 64;
        const float* s1 = x + ((size_t)(8 + h) * N_SEQ + nb * 64) * 64;
        for (int r = ly; r < 64; r += 8) {
            t0[r][lx] = s0[r * 64 + lx];
            t1[r][lx] = s1[r * 64 + lx];
        }
        __syncthreads();
        for (int r = ly; r < 64; r += 8) {
            float2* dst = xt2 + (size_t)(h * 64 + r) * N_SEQ + nb * 64;
            dst[lx] = make_float2(t0[lx][r], t1[lx][r]);
        }
        return;
    }

    float (*ubuf)[65] = (float (*)[65])smem;               // [pos][feat]
    float (*sums)[17] = (float (*)[17])(smem + 8320);
    float4* wl        = (float4*)(smem + 10496);           // weight area

    // ---- hidden chain: thread = (p = tid&31, s = tid>>5 feature-quad) ----
    {
        const int p = tid & 31;
        const int s = tid >> 5;       // 0..15, features s*4..s*4+3
        const int pos = blockIdx.x * 32 + p;
        float v;
        if (pos == 0 || pos == N_SEQ) v = 1.0f;
        else if (pos < N_SEQ)         v = 1.0f / (float)(pos + 1);
        else                          v = -1.0f / (float)(2 * N_SEQ + 1 - pos);

        float h[4];
#pragma unroll
        for (int i = 0; i < 4; ++i) {
            int f = s * 4 + i;
            h[i] = v * w_in[f] + b_in[f];
        }
        for (int L = 0; L < LAYERS; ++L) {
            const float4* wsrc = (const float4*)(w_hid + L * 4096);
            wl[tid] = wsrc[tid];
            wl[tid + 512] = wsrc[tid + 512];
            float s2 = h[0]*h[0] + h[1]*h[1] + h[2]*h[2] + h[3]*h[3];
            sums[p][s] = s2;
            __syncthreads();
            float tot = 0.f;
#pragma unroll
            for (int g = 0; g < 16; ++g) tot += sums[p][g];
            float r = rsqrtf(tot * (1.f / 64.f) + 1e-8f);
#pragma unroll
            for (int i = 0; i < 4; ++i)
                ubuf[p][s * 4 + i] = fmaxf(h[i] * r, 0.f);
            __syncthreads();           // ubuf + wl ready
            float acc[4];
#pragma unroll
            for (int i = 0; i < 4; ++i) acc[i] = b_hid[L * 64 + s * 4 + i];
#pragma unroll 8
            for (int j = 0; j < 64; ++j) {
                float uj = ubuf[p][j];
                float4 w = wl[j * 16 + s];
                acc[0] = fmaf(uj, w.x, acc[0]); acc[1] = fmaf(uj, w.y, acc[1]);
                acc[2] = fmaf(uj, w.z, acc[2]); acc[3] = fmaf(uj, w.w, acc[3]);
            }
#pragma unroll
            for (int i = 0; i < 4; ++i) h[i] = acc[i];
            __syncthreads();           // before wl/sums/ubuf overwrite
        }
        // final RMS + relu -> ubuf
        float s2 = h[0]*h[0] + h[1]*h[1] + h[2]*h[2] + h[3]*h[3];
        sums[p][s] = s2;
        __syncthreads();
        float tot = 0.f;
#pragma unroll
        for (int g = 0; g < 16; ++g) tot += sums[p][g];
        float r = rsqrtf(tot * (1.f / 64.f) + 1e-8f);
#pragma unroll
        for (int i = 0; i < 4; ++i)
            ubuf[p][s * 4 + i] = fmaxf(h[i] * r, 0.f);
        __syncthreads();
    }

    // ---- out GEMM: thread = (o = tid>>3 octet, pg = tid&7 pos-group of 4) ----
    {
        const int o  = tid >> 3;
        const int pg = tid & 7;
        const int pos0 = blockIdx.x * 32;
        float4* wt = wl;               // [16][128] float4: row jj = 128 float4
        float acc[8][4];
#pragma unroll
        for (int ii = 0; ii < 8; ++ii) {
            float bo = b_out[o * 8 + ii];
#pragma unroll
            for (int i = 0; i < 4; ++i) acc[ii][i] = bo;
        }
        for (int jc = 0; jc < 4; ++jc) {
            float4 wreg[4];
#pragma unroll
            for (int k = 0; k < 4; ++k) {
                int i4 = k * 512 + tid;           // 0..2047
                int jj = i4 >> 7, f4 = i4 & 127;
                wreg[k] = *(const float4*)(w_out + (jc * 16 + jj) * 512 + f4 * 4);
            }
            __syncthreads();           // prior wt reads done (1st iter: hidden's wl)
#pragma unroll
            for (int k = 0; k < 4; ++k) {
                int i4 = k * 512 + tid;
                wt[i4] = wreg[k];
            }
            __syncthreads();
#pragma unroll
            for (int jj = 0; jj < 16; ++jj) {
                int j = jc * 16 + jj;
                float4 w0 = wt[jj * 128 + o * 2];
                float4 w1 = wt[jj * 128 + o * 2 + 1];
                float u0 = ubuf[pg * 4 + 0][j];
                float u1 = ubuf[pg * 4 + 1][j];
                float u2 = ubuf[pg * 4 + 2][j];
                float u3 = ubuf[pg * 4 + 3][j];
                acc[0][0] = fmaf(u0, w0.x, acc[0][0]); acc[0][1] = fmaf(u1, w0.x, acc[0][1]);
                acc[0][2] = fmaf(u2, w0.x, acc[0][2]); acc[0][3] = fmaf(u3, w0.x, acc[0][3]);
                acc[1][0] = fmaf(u0, w0.y, acc[1][0]); acc[1][1] = fmaf(u1, w0.y, acc[1][1]);
                acc[1][2] = fmaf(u2, w0.y, acc[1][2]); acc[1][3] = fmaf(u3, w0.y, acc[1][3]);
                acc[2][0] = fmaf(u0, w0.z, acc[2][0]); acc[2][1] = fmaf(u1, w0.z, acc[2][1]);
                acc[2][2] = fmaf(u2, w0.z, acc[2][2]); acc[2][3] = fmaf(u3, w0.z, acc[2][3]);
                acc[3][0] = fmaf(u0, w0.w, acc[3][0]); acc[3][1] = fmaf(u1, w0.w, acc[3][1]);
                acc[3][2] = fmaf(u2, w0.w, acc[3][2]); acc[3][3] = fmaf(u3, w0.w, acc[3][3]);
                acc[4][0] = fmaf(u0, w1.x, acc[4][0]); acc[4][1] = fmaf(u1, w1.x, acc[4][1]);
                acc[4][2] = fmaf(u2, w1.x, acc[4][2]); acc[4][3] = fmaf(u3, w1.x, acc[4][3]);
                acc[5][0] = fmaf(u0, w1.y, acc[5][0]); acc[5][1] = fmaf(u1, w1.y, acc[5][1]);
                acc[5][2] = fmaf(u2, w1.y, acc[5][2]); acc[5][3] = fmaf(u3, w1.y, acc[5][3]);
                acc[6][0] = fmaf(u0, w1.z, acc[6][0]); acc[6][1] = fmaf(u1, w1.z, acc[6][1]);
                acc[6][2] = fmaf(u2, w1.z, acc[6][2]); acc[6][3] = fmaf(u3, w1.z, acc[6][3]);
                acc[7][0] = fmaf(u0, w1.w, acc[7][0]); acc[7][1] = fmaf(u1, w1.w, acc[7][1]);
                acc[7][2] = fmaf(u2, w1.w, acc[7][2]); acc[7][3] = fmaf(u3, w1.w, acc[7][3]);
            }
            __syncthreads();           // wt reads done before next stage
        }
#pragma unroll
        for (int ii = 0; ii < 8; ++ii) {
            int f = o * 8 + ii;
#pragma unroll
            for (int i = 0; i < 4; ++i)
                a_t[(size_t)f * N_FFT + pos0 + pg * 4 + i] = acc[ii][i];
        }
    }
}

// ========== afft: A forward FFT only; spectrum to global (thread-major order,
// 128 B/thread contiguous both on store and on zconv's load). No array lives
// across an FFT phase -> comfortably under the 128-VGPR cap (R5: conv at the
// cap spilled ~285 MB/rep). ==========
__global__ __launch_bounds__(FT, 2) void afft_kernel(const float* __restrict__ a_t,
                                                     float2* __restrict__ aspec)
{
    __shared__ __align__(16) float2 buf[8704];   // 69632 B
    const int tid = threadIdx.x;
    const int lane = tid & 63;
    const int C = (tid >> 6) << 10;
    const int hd = blockIdx.x;

    {
        const float2* asrc = (const float2*)(a_t + (size_t)hd * N_FFT);
        float2 av[8];
#pragma unroll
        for (int p = 0; p < 8; ++p) av[p] = asrc[tid + 512 * p];
        float xa[8], xb[8];
#pragma unroll
        for (int p = 0; p < 8; ++p) { xa[p] = av[p].x; xb[p] = av[p].y; }
        float2 X0[8], X1[8];
        ahead8(xa, 2 * tid,     X0);
        ahead8(xb, 2 * tid + 1, X1);
#pragma unroll
        for (int q = 0; q < 8; ++q)
            *(float4*)&buf[IDX2(q * 1024 + 2 * tid)] =
                make_float4(X0[q].x, X0[q].y, X1[q].x, X1[q].y);
    }
    __syncthreads();
    wpass16_fwd<1024>(buf, C, lane);
    WSYNC();
    wpass16_fwd<64>(buf, C, lane);
    WSYNC();
    {   // tail + store spectrum (thread t owns elements [16t, 16t+16) = C + 16*lane ..)
        float2 asp[16];
#pragma unroll
        for (int k = 0; k < 8; ++k) {
            float4 v = *(const float4*)&buf[IDX2(C + 16 * lane + 2 * k)];
            asp[2 * k]     = make_float2(v.x, v.y);
            asp[2 * k + 1] = make_float2(v.z, v.w);
        }
        tail4_fwd(asp);
        float4* dst = (float4*)(aspec + (size_t)hd * N_FFT) + tid * 8;
#pragma unroll
        for (int k = 0; k < 8; ++k)
            dst[k] = make_float4(asp[2 * k].x, asp[2 * k].y,
                                 asp[2 * k + 1].x, asp[2 * k + 1].y);
    }
}

// ========== zconv: Z forward FFT + pointwise (A spectrum loaded from global at
// the multiply, coalesced 128 B/thread) + inverse FFT + store [0,4096). ==========
__global__ __launch_bounds__(FT, 2) void zconv_kernel(const float2* __restrict__ aspec,
                                                      const float2* __restrict__ xt2,
                                                      float2* __restrict__ out_t2)
{
    __shared__ __align__(16) float2 buf[8704];
    const int tid = threadIdx.x;
    const int lane = tid & 63;
    const int C = (tid >> 6) << 10;
    const int hd = blockIdx.x;

    {   // Z head: radix-8 with upper half zero (zero padding)
        const float4* zsrc = (const float4*)(xt2 + (size_t)hd * N_SEQ);
        float4 zl[4];
#pragma unroll
        for (int p = 0; p < 4; ++p) zl[p] = zsrc[tid + 512 * p];
        float2 z0[4], z1[4];
#pragma unroll
        for (int p = 0; p < 4; ++p) {
            z0[p] = make_float2(zl[p].x, zl[p].y);
            z1[p] = make_float2(zl[p].z, zl[p].w);
        }
        float2 X0[8], X1[8];
        zhead8(z0, 2 * tid,     X0);
        zhead8(z1, 2 * tid + 1, X1);
#pragma unroll
        for (int q = 0; q < 8; ++q)
            *(float4*)&buf[IDX2(q * 1024 + 2 * tid)] =
                make_float4(X0[q].x, X0[q].y, X1[q].x, X1[q].y);
    }
    __syncthreads();
    wpass16_fwd<1024>(buf, C, lane);
    WSYNC();
    wpass16_fwd<64>(buf, C, lane);
    WSYNC();
    {   // Z tail + pointwise (A spectrum from global, 1/N fused) + inverse tail
        const float4* ap = (const float4*)(aspec + (size_t)hd * N_FFT) + tid * 8;
        float4 aw[8];
#pragma unroll
        for (int k = 0; k < 8; ++k) aw[k] = ap[k];   // HBM/L2 latency hides under LDS reads below
        float2 zp[16];
#pragma unroll
        for (int k = 0; k < 8; ++k) {
            float4 v = *(const float4*)&buf[IDX2(C + 16 * lane + 2 * k)];
            zp[2 * k]     = make_float2(v.x, v.y);
            zp[2 * k + 1] = make_float2(v.z, v.w);
        }
        tail4_fwd(zp);
        const float inv = 1.0f / (float)N_FFT;
#pragma unroll
        for (int k = 0; k < 8; ++k) {
            float2 a0 = make_float2(aw[k].x, aw[k].y);
            float2 a1 = make_float2(aw[k].z, aw[k].w);
            float2 m0 = cmulf(zp[2 * k],     a0);
            float2 m1 = cmulf(zp[2 * k + 1], a1);
            zp[2 * k]     = make_float2(m0.x * inv, m0.y * inv);
            zp[2 * k + 1] = make_float2(m1.x * inv, m1.y * inv);
        }
        tail4_inv(zp);
#pragma unroll
        for (int k = 0; k < 8; ++k)
            *(float4*)&buf[IDX2(C + 16 * lane + 2 * k)] =
                make_float4(zp[2 * k].x, zp[2 * k].y, zp[2 * k + 1].x, zp[2 * k + 1].y);
    }
    WSYNC();
    wpass16_inv<64>(buf, C, lane);
    WSYNC();
    wpass16_inv<1024>(buf, C, lane);
    __syncthreads();
    {   // inverse head: conj-twiddled half-output radix-8, store [0,4096)
        float2 v0[8], v1[8];
#pragma unroll
        for (int q = 0; q < 8; ++q) {
            float4 r = *(const float4*)&buf[IDX2(q * 1024 + 2 * tid)];
            v0[q] = make_float2(r.x, r.y);
            v1[q] = make_float2(r.z, r.w);
        }
        float2 u0[4], u1[4];
        ihead8(v0, 2 * tid,     u0);
        ihead8(v1, 2 * tid + 1, u1);
        float4* dst = (float4*)(out_t2 + (size_t)hd * N_SEQ);
#pragma unroll
        for (int p = 0; p < 4; ++p)
            dst[tid + 512 * p] = make_float4(u0[p].x, u0[p].y, u1[p].x, u1[p].y);
    }
}

// ========== transpose out: out_t2[hd][n] -> out (2,8,N,64) ==========
__global__ __launch_bounds__(256) void transpose_o_kernel(const float2* __restrict__ out_t2,
                                                          float* __restrict__ out)
{
    __shared__ float t0[64][65];
    __shared__ float t1[64][65];
    int h = blockIdx.x >> 6;
    int nb = blockIdx.x & 63;
    int lx = threadIdx.x & 63;
    int ly = threadIdx.x >> 6;
    for (int r = ly; r < 64; r += 4) {
        float2 v = out_t2[(size_t)(h * 64 + r) * N_SEQ + nb * 64 + lx];
        t0[r][lx] = v.x;
        t1[r][lx] = v.y;
    }
    __syncthreads();
    float* d0 = out + ((size_t)h * N_SEQ + nb * 64) * 64;
    float* d1 = out + ((size_t)(8 + h) * N_SEQ + nb * 64) * 64;
    for (int r = ly; r < 64; r += 4) {
        d0[r * 64 + lx] = t0[lx][r];
        d1[r * 64 + lx] = t1[lx][r];
    }
}

extern "C" void kernel_launch(void* const* d_in, const int* in_sizes, int n_in,
                              void* d_out, int out_size, void* d_ws, size_t ws_size,
                              hipStream_t stream)
{
    const float* x     = (const float*)d_in[0];
    const float* w_in  = (const float*)d_in[1];
    const float* b_in  = (const float*)d_in[2];
    const float* w_hid = (const float*)d_in[3];
    const float* b_hid = (const float*)d_in[4];
    const float* w_out = (const float*)d_in[5];
    const float* b_out = (const float*)d_in[6];
    float* out = (float*)d_out;

    char* ws = (char*)d_ws;
    float2* xt2    = (float2*)ws;                               // 16 MB
    float*  a_t    = (float*)(ws + (size_t)16 * 1024 * 1024);   // 16 MB
    float2* out_t2 = (float2*)(ws + (size_t)32 * 1024 * 1024);  // 16 MB
    float2* aspec  = (float2*)(ws + (size_t)48 * 1024 * 1024);  // 32 MB (A spectrum)

    prep_kernel<<<768, 512, 0, stream>>>(x, w_in, b_in, w_hid, b_hid, w_out, b_out,
                                         a_t, xt2);
    afft_kernel<<<512, FT, 0, stream>>>(a_t, aspec);
    zconv_kernel<<<512, FT, 0, stream>>>(aspec, xt2, out_t2);
    transpose_o_kernel<<<512, 256, 0, stream>>>(out_t2, out);
}

// Round 7
// 144.704 us; speedup vs baseline: 2.0745x; 1.0461x over previous
//
#include <hip/hip_runtime.h>

#define N_SEQ 4096
#define N_FFT 8192
#define LAYERS 3
#define FT 512                 // threads per FFT block
#define PIDX(i) ((i) + ((i) >> 5))   // +1 word per 32 -> all passes 2-way (free)

// ===== SESSION LEDGER (MI355X, direct measurements only) =====
// R0: block-wide conv = 54-57us rocprof (VGPR 104, no spill), total 143.3. BEST.
// R1: launch_bounds arg2 behaves as CUDA minBlocksPerCU: (512,4)->64-VGPR cap
//     -> 300MB scratch; (512,2)->128 cap. Keep (512,2) everywhere w/ 512 thr.
// R2-R6: wave-local conv (4 barriers, WSYNC) ~120us inferred - SLOWER than the
//     12-barrier original regardless of spill (R6 split afft/zconv: null).
//     Root cause never isolated; structure abandoned.
// R4: hipLaunchCooperativeKernel crashes the harness. Never again.
// R5: dur_us excludes the ~43-45us workspace-poison fill; rocprof top-5 can
//     silently DROP real kernel rows (NaN-counter artifact) - "kernel < fill"
//     inferences from absence are unsafe.
// R7: revert conv to R0-exact (fastest measured). conv>fill -> visible again.

// =============== radix-16 pass: two DIF stages (M then M/4) in registers ===============
template<int M>
__device__ inline void pass16_fwd(float* re, float* im, int tid)
{
    const int Q = M >> 4;
    const int j = tid & (Q - 1);
    const int G = tid / Q;
    const int base = G * M + j;
    const float KR[4] = {1.f, 0.9238795325f, 0.7071067812f, 0.3826834324f};
    const float KI[4] = {0.f, -0.3826834324f, -0.7071067812f, -0.9238795325f};
    float xr[4][4], xi[4][4];
#pragma unroll
    for (int a = 0; a < 4; ++a)
#pragma unroll
        for (int b = 0; b < 4; ++b) {
            int idx = PIDX(base + a * (M >> 2) + b * Q);
            xr[a][b] = re[idx]; xi[a][b] = im[idx];
        }
    float cj, sj;
    __sincosf(-6.283185307179586f / (float)M * (float)j, &sj, &cj);
#pragma unroll
    for (int b = 0; b < 4; ++b) {
        float c1 = cj * KR[b] - sj * KI[b];
        float s1 = cj * KI[b] + sj * KR[b];
        float c2 = c1 * c1 - s1 * s1, s2 = 2.f * c1 * s1;
        float c3 = c2 * c1 - s2 * s1, s3 = c2 * s1 + s2 * c1;
        float ar = xr[0][b] + xr[2][b], ai = xi[0][b] + xi[2][b];
        float br = xr[0][b] - xr[2][b], bi = xi[0][b] - xi[2][b];
        float cr = xr[1][b] + xr[3][b], ci = xi[1][b] + xi[3][b];
        float dr = xi[1][b] - xi[3][b], di = -(xr[1][b] - xr[3][b]);
        xr[0][b] = ar + cr;               xi[0][b] = ai + ci;
        float t1r = br + dr, t1i = bi + di;
        xr[1][b] = t1r * c1 - t1i * s1;   xi[1][b] = t1r * s1 + t1i * c1;
        float t2r = ar - cr, t2i = ai - ci;
        xr[2][b] = t2r * c2 - t2i * s2;   xi[2][b] = t2r * s2 + t2i * c2;
        float t3r = br - dr, t3i = bi - di;
        xr[3][b] = t3r * c3 - t3i * s3;   xi[3][b] = t3r * s3 + t3i * c3;
    }
    {
        float e1c = cj * cj - sj * sj, e1s = 2.f * cj * sj;      // W^{2j}
        float c1 = e1c * e1c - e1s * e1s, s1 = 2.f * e1c * e1s;  // W^{4j}
        float c2 = c1 * c1 - s1 * s1, s2 = 2.f * c1 * s1;
        float c3 = c2 * c1 - s2 * s1, s3 = c2 * s1 + s2 * c1;
#pragma unroll
        for (int a = 0; a < 4; ++a) {
            float ar = xr[a][0] + xr[a][2], ai = xi[a][0] + xi[a][2];
            float br = xr[a][0] - xr[a][2], bi = xi[a][0] - xi[a][2];
            float cr = xr[a][1] + xr[a][3], ci = xi[a][1] + xi[a][3];
            float dr = xi[a][1] - xi[a][3], di = -(xr[a][1] - xr[a][3]);
            xr[a][0] = ar + cr;               xi[a][0] = ai + ci;
            float t1r = br + dr, t1i = bi + di;
            xr[a][1] = t1r * c1 - t1i * s1;   xi[a][1] = t1r * s1 + t1i * c1;
            float t2r = ar - cr, t2i = ai - ci;
            xr[a][2] = t2r * c2 - t2i * s2;   xi[a][2] = t2r * s2 + t2i * c2;
            float t3r = br - dr, t3i = bi - di;
            xr[a][3] = t3r * c3 - t3i * s3;   xi[a][3] = t3r * s3 + t3i * c3;
        }
    }
#pragma unroll
    for (int a = 0; a < 4; ++a)
#pragma unroll
        for (int b = 0; b < 4; ++b) {
            int idx = PIDX(base + a * (M >> 2) + b * Q);
            re[idx] = xr[a][b]; im[idx] = xi[a][b];
        }
}

template<int M>
__device__ inline void pass16_inv(float* re, float* im, int tid)
{
    const int Q = M >> 4;
    const int j = tid & (Q - 1);
    const int G = tid / Q;
    const int base = G * M + j;
    const float KR[4] = {1.f, 0.9238795325f, 0.7071067812f, 0.3826834324f};
    const float KI[4] = {0.f, 0.3826834324f, 0.7071067812f, 0.9238795325f};   // conj
    float xr[4][4], xi[4][4];
#pragma unroll
    for (int a = 0; a < 4; ++a)
#pragma unroll
        for (int b = 0; b < 4; ++b) {
            int idx = PIDX(base + a * (M >> 2) + b * Q);
            xr[a][b] = re[idx]; xi[a][b] = im[idx];
        }
    float cj, sj;
    __sincosf(6.283185307179586f / (float)M * (float)j, &sj, &cj);
    {
        float e1c = cj * cj - sj * sj, e1s = 2.f * cj * sj;
        float c1 = e1c * e1c - e1s * e1s, s1 = 2.f * e1c * e1s;
        float c2 = c1 * c1 - s1 * s1, s2 = 2.f * c1 * s1;
        float c3 = c2 * c1 - s2 * s1, s3 = c2 * s1 + s2 * c1;
#pragma unroll
        for (int a = 0; a < 4; ++a) {
            float t0r = xr[a][0], t0i = xi[a][0];
            float t1r = xr[a][1] * c1 - xi[a][1] * s1, t1i = xr[a][1] * s1 + xi[a][1] * c1;
            float t2r = xr[a][2] * c2 - xi[a][2] * s2, t2i = xr[a][2] * s2 + xi[a][2] * c2;
            float t3r = xr[a][3] * c3 - xi[a][3] * s3, t3i = xr[a][3] * s3 + xi[a][3] * c3;
            float pr = t0r + t2r, pi = t0i + t2i;
            float qr = t0r - t2r, qi = t0i - t2i;
            float rr = t1r + t3r, ri = t1i + t3i;
            float sr = -(t1i - t3i), si = t1r - t3r;
            xr[a][0] = pr + rr; xi[a][0] = pi + ri;
            xr[a][1] = qr + sr; xi[a][1] = qi + si;
            xr[a][2] = pr - rr; xi[a][2] = pi - ri;
            xr[a][3] = qr - sr; xi[a][3] = qi - si;
        }
    }
#pragma unroll
    for (int b = 0; b < 4; ++b) {
        float c1 = cj * KR[b] - sj * KI[b];
        float s1 = cj * KI[b] + sj * KR[b];
        float c2 = c1 * c1 - s1 * s1, s2 = 2.f * c1 * s1;
        float c3 = c2 * c1 - s2 * s1, s3 = c2 * s1 + s2 * c1;
        float t0r = xr[0][b], t0i = xi[0][b];
        float t1r = xr[1][b] * c1 - xi[1][b] * s1, t1i = xr[1][b] * s1 + xi[1][b] * c1;
        float t2r = xr[2][b] * c2 - xi[2][b] * s2, t2i = xr[2][b] * s2 + xi[2][b] * c2;
        float t3r = xr[3][b] * c3 - xi[3][b] * s3, t3i = xr[3][b] * s3 + xi[3][b] * c3;
        float pr = t0r + t2r, pi = t0i + t2i;
        float qr = t0r - t2r, qi = t0i - t2i;
        float rr = t1r + t3r, ri = t1i + t3i;
        float sr = -(t1i - t3i), si = t1r - t3r;
        xr[0][b] = pr + rr; xi[0][b] = pi + ri;
        xr[1][b] = qr + sr; xi[1][b] = qi + si;
        xr[2][b] = pr - rr; xi[2][b] = pi - ri;
        xr[3][b] = qr - sr; xi[3][b] = qi - si;
    }
#pragma unroll
    for (int a = 0; a < 4; ++a)
#pragma unroll
        for (int b = 0; b < 4; ++b) {
            int idx = PIDX(base + a * (M >> 2) + b * Q);
            re[idx] = xr[a][b]; im[idx] = xi[a][b];
        }
}

// ======= radix-8 tail (stage m=8 + r2), contiguous 8 points, constant twiddles =======
__device__ inline void fwd8(float* zr, float* zi, int o)
{
    const float R = 0.70710678118654752f;
    {
        float ar = zr[o] + zr[o+4], ai = zi[o] + zi[o+4];
        float br = zr[o] - zr[o+4], bi = zi[o] - zi[o+4];
        float cr = zr[o+2] + zr[o+6], ci = zi[o+2] + zi[o+6];
        float dr = zi[o+2] - zi[o+6], di = -(zr[o+2] - zr[o+6]);
        zr[o]   = ar + cr; zi[o]   = ai + ci;
        zr[o+2] = br + dr; zi[o+2] = bi + di;
        zr[o+4] = ar - cr; zi[o+4] = ai - ci;
        zr[o+6] = br - dr; zi[o+6] = bi - di;
    }
    {
        float ar = zr[o+1] + zr[o+5], ai = zi[o+1] + zi[o+5];
        float br = zr[o+1] - zr[o+5], bi = zi[o+1] - zi[o+5];
        float cr = zr[o+3] + zr[o+7], ci = zi[o+3] + zi[o+7];
        float dr = zi[o+3] - zi[o+7], di = -(zr[o+3] - zr[o+7]);
        zr[o+1] = ar + cr; zi[o+1] = ai + ci;
        float t1r = br + dr, t1i = bi + di;
        zr[o+3] = R * (t1r + t1i); zi[o+3] = R * (t1i - t1r);
        float t2r = ar - cr, t2i = ai - ci;
        zr[o+5] = t2i;  zi[o+5] = -t2r;
        float t3r = br - dr, t3i = bi - di;
        zr[o+7] = R * (t3i - t3r); zi[o+7] = -R * (t3r + t3i);
    }
#pragma unroll
    for (int p = 0; p < 8; p += 2) {
        float ur = zr[o+p], ui = zi[o+p], vr = zr[o+p+1], vi = zi[o+p+1];
        zr[o+p]   = ur + vr; zi[o+p]   = ui + vi;
        zr[o+p+1] = ur - vr; zi[o+p+1] = ui - vi;
    }
}

__device__ inline void inv8(float* zr, float* zi, int o)
{
    const float R = 0.70710678118654752f;
#pragma unroll
    for (int p = 0; p < 8; p += 2) {
        float ur = zr[o+p], ui = zi[o+p], vr = zr[o+p+1], vi = zi[o+p+1];
        zr[o+p]   = ur + vr; zi[o+p]   = ui + vi;
        zr[o+p+1] = ur - vr; zi[o+p+1] = ui - vi;
    }
    {
        float t0r = zr[o],   t0i = zi[o];
        float t1r = zr[o+2], t1i = zi[o+2];
        float t2r = zr[o+4], t2i = zi[o+4];
        float t3r = zr[o+6], t3i = zi[o+6];
        float pr = t0r + t2r, pi = t0i + t2i;
        float qr = t0r - t2r, qi = t0i - t2i;
        float rr = t1r + t3r, ri = t1i + t3i;
        float sr = -(t1i - t3i), si = t1r - t3r;
        zr[o]   = pr + rr; zi[o]   = pi + ri;
        zr[o+2] = qr + sr; zi[o+2] = qi + si;
        zr[o+4] = pr - rr; zi[o+4] = pi - ri;
        zr[o+6] = qr - sr; zi[o+6] = qi - si;
    }
    {
        float t0r = zr[o+1], t0i = zi[o+1];
        float yr = zr[o+3], yi = zi[o+3];
        float t1r = R * (yr - yi), t1i = R * (yr + yi);
        yr = zr[o+5]; yi = zi[o+5];
        float t2r = -yi, t2i = yr;
        yr = zr[o+7]; yi = zi[o+7];
        float t3r = -R * (yr + yi), t3i = R * (yr - yi);
        float pr = t0r + t2r, pi = t0i + t2i;
        float qr = t0r - t2r, qi = t0i - t2i;
        float rr = t1r + t3r, ri = t1i + t3i;
        float sr = -(t1i - t3i), si = t1r - t3r;
        zr[o+1] = pr + rr; zi[o+1] = pi + ri;
        zr[o+3] = qr + sr; zi[o+3] = qi + si;
        zr[o+5] = pr - rr; zi[o+5] = pi - ri;
        zr[o+7] = qr - sr; zi[o+7] = qi - si;
    }
}

// ============ prep: [blocks 0..255] RPE (32 pos/block, all 512 outputs) -> a_t
//              [blocks 256..767] transpose x -> xt2 ============
__global__ __launch_bounds__(512, 2) void prep_kernel(
    const float* __restrict__ x,
    const float* __restrict__ w_in, const float* __restrict__ b_in,
    const float* __restrict__ w_hid, const float* __restrict__ b_hid,
    const float* __restrict__ w_out, const float* __restrict__ b_out,
    float* __restrict__ a_t, float2* __restrict__ xt2)
{
    __shared__ __align__(16) char smem[43264];
    const int tid = threadIdx.x;

    if (blockIdx.x >= 256) {
        // ---- transpose x: (2,8,N,64) -> xt2[hd][n] = (x_b0, x_b1) ----
        float (*t0)[65] = (float (*)[65])smem;
        float (*t1)[65] = (float (*)[65])(smem + 16640);
        int bb = blockIdx.x - 256;
        int h = bb >> 6;
        int nb = bb & 63;
        int lx = tid & 63;
        int ly = tid >> 6;          // 0..7
        const float* s0 = x + ((size_t)h * N_SEQ + nb * 64) * 64;
        const float* s1 = x + ((size_t)(8 + h) * N_SEQ + nb * 64) * 64;
        for (int r = ly; r < 64; r += 8) {
            t0[r][lx] = s0[r * 64 + lx];
            t1[r][lx] = s1[r * 64 + lx];
        }
        __syncthreads();
        for (int r = ly; r < 64; r += 8) {
            float2* dst = xt2 + (size_t)(h * 64 + r) * N_SEQ + nb * 64;
            dst[lx] = make_float2(t0[lx][r], t1[lx][r]);
        }
        return;
    }

    float (*ubuf)[65] = (float (*)[65])smem;               // [pos][feat]
    float (*sums)[17] = (float (*)[17])(smem + 8320);
    float4* wl        = (float4*)(smem + 10496);           // weight area

    // ---- hidden chain: thread = (p = tid&31, s = tid>>5 feature-quad) ----
    {
        const int p = tid & 31;
        const int s = tid >> 5;       // 0..15, features s*4..s*4+3
        const int pos = blockIdx.x * 32 + p;
        float v;
        if (pos == 0 || pos == N_SEQ) v = 1.0f;
        else if (pos < N_SEQ)         v = 1.0f / (float)(pos + 1);
        else                          v = -1.0f / (float)(2 * N_SEQ + 1 - pos);

        float h[4];
#pragma unroll
        for (int i = 0; i < 4; ++i) {
            int f = s * 4 + i;
            h[i] = v * w_in[f] + b_in[f];
        }
        for (int L = 0; L < LAYERS; ++L) {
            const float4* wsrc = (const float4*)(w_hid + L * 4096);
            wl[tid] = wsrc[tid];
            wl[tid + 512] = wsrc[tid + 512];
            float s2 = h[0]*h[0] + h[1]*h[1] + h[2]*h[2] + h[3]*h[3];
            sums[p][s] = s2;
            __syncthreads();
            float tot = 0.f;
#pragma unroll
            for (int g = 0; g < 16; ++g) tot += sums[p][g];
            float r = rsqrtf(tot * (1.f / 64.f) + 1e-8f);
#pragma unroll
            for (int i = 0; i < 4; ++i)
                ubuf[p][s * 4 + i] = fmaxf(h[i] * r, 0.f);
            __syncthreads();           // ubuf + wl ready
            float acc[4];
#pragma unroll
            for (int i = 0; i < 4; ++i) acc[i] = b_hid[L * 64 + s * 4 + i];
#pragma unroll 8
            for (int j = 0; j < 64; ++j) {
                float uj = ubuf[p][j];
                float4 w = wl[j * 16 + s];
                acc[0] = fmaf(uj, w.x, acc[0]); acc[1] = fmaf(uj, w.y, acc[1]);
                acc[2] = fmaf(uj, w.z, acc[2]); acc[3] = fmaf(uj, w.w, acc[3]);
            }
#pragma unroll
            for (int i = 0; i < 4; ++i) h[i] = acc[i];
            __syncthreads();           // before wl/sums/ubuf overwrite
        }
        // final RMS + relu -> ubuf
        float s2 = h[0]*h[0] + h[1]*h[1] + h[2]*h[2] + h[3]*h[3];
        sums[p][s] = s2;
        __syncthreads();
        float tot = 0.f;
#pragma unroll
        for (int g = 0; g < 16; ++g) tot += sums[p][g];
        float r = rsqrtf(tot * (1.f / 64.f) + 1e-8f);
#pragma unroll
        for (int i = 0; i < 4; ++i)
            ubuf[p][s * 4 + i] = fmaxf(h[i] * r, 0.f);
        __syncthreads();
    }

    // ---- out GEMM: thread = (o = tid>>3 octet, pg = tid&7 pos-group of 4) ----
    {
        const int o  = tid >> 3;
        const int pg = tid & 7;
        const int pos0 = blockIdx.x * 32;
        float4* wt = wl;               // [16][128] float4: row jj = 128 float4
        float acc[8][4];
#pragma unroll
        for (int ii = 0; ii < 8; ++ii) {
            float bo = b_out[o * 8 + ii];
#pragma unroll
            for (int i = 0; i < 4; ++i) acc[ii][i] = bo;
        }
        for (int jc = 0; jc < 4; ++jc) {
            float4 wreg[4];
#pragma unroll
            for (int k = 0; k < 4; ++k) {
                int i4 = k * 512 + tid;           // 0..2047
                int jj = i4 >> 7, f4 = i4 & 127;
                wreg[k] = *(const float4*)(w_out + (jc * 16 + jj) * 512 + f4 * 4);
            }
            __syncthreads();           // prior wt reads done (1st iter: hidden's wl)
#pragma unroll
            for (int k = 0; k < 4; ++k) {
                int i4 = k * 512 + tid;
                wt[i4] = wreg[k];
            }
            __syncthreads();
#pragma unroll
            for (int jj = 0; jj < 16; ++jj) {
                int j = jc * 16 + jj;
                float4 w0 = wt[jj * 128 + o * 2];
                float4 w1 = wt[jj * 128 + o * 2 + 1];
                float u0 = ubuf[pg * 4 + 0][j];
                float u1 = ubuf[pg * 4 + 1][j];
                float u2 = ubuf[pg * 4 + 2][j];
                float u3 = ubuf[pg * 4 + 3][j];
                acc[0][0] = fmaf(u0, w0.x, acc[0][0]); acc[0][1] = fmaf(u1, w0.x, acc[0][1]);
                acc[0][2] = fmaf(u2, w0.x, acc[0][2]); acc[0][3] = fmaf(u3, w0.x, acc[0][3]);
                acc[1][0] = fmaf(u0, w0.y, acc[1][0]); acc[1][1] = fmaf(u1, w0.y, acc[1][1]);
                acc[1][2] = fmaf(u2, w0.y, acc[1][2]); acc[1][3] = fmaf(u3, w0.y, acc[1][3]);
                acc[2][0] = fmaf(u0, w0.z, acc[2][0]); acc[2][1] = fmaf(u1, w0.z, acc[2][1]);
                acc[2][2] = fmaf(u2, w0.z, acc[2][2]); acc[2][3] = fmaf(u3, w0.z, acc[2][3]);
                acc[3][0] = fmaf(u0, w0.w, acc[3][0]); acc[3][1] = fmaf(u1, w0.w, acc[3][1]);
                acc[3][2] = fmaf(u2, w0.w, acc[3][2]); acc[3][3] = fmaf(u3, w0.w, acc[3][3]);
                acc[4][0] = fmaf(u0, w1.x, acc[4][0]); acc[4][1] = fmaf(u1, w1.x, acc[4][1]);
                acc[4][2] = fmaf(u2, w1.x, acc[4][2]); acc[4][3] = fmaf(u3, w1.x, acc[4][3]);
                acc[5][0] = fmaf(u0, w1.y, acc[5][0]); acc[5][1] = fmaf(u1, w1.y, acc[5][1]);
                acc[5][2] = fmaf(u2, w1.y, acc[5][2]); acc[5][3] = fmaf(u3, w1.y, acc[5][3]);
                acc[6][0] = fmaf(u0, w1.z, acc[6][0]); acc[6][1] = fmaf(u1, w1.z, acc[6][1]);
                acc[6][2] = fmaf(u2, w1.z, acc[6][2]); acc[6][3] = fmaf(u3, w1.z, acc[6][3]);
                acc[7][0] = fmaf(u0, w1.w, acc[7][0]); acc[7][1] = fmaf(u1, w1.w, acc[7][1]);
                acc[7][2] = fmaf(u2, w1.w, acc[7][2]); acc[7][3] = fmaf(u3, w1.w, acc[7][3]);
            }
            __syncthreads();           // wt reads done before next stage
        }
#pragma unroll
        for (int ii = 0; ii < 8; ++ii) {
            int f = o * 8 + ii;
#pragma unroll
            for (int i = 0; i < 4; ++i)
                a_t[(size_t)f * N_FFT + pos0 + pg * 4 + i] = acc[ii][i];
        }
    }
}

// ========== conv: A-FFT (spectrum kept in regs) + z-FFT + mult + iFFT ==========
// R0-exact structure: 12 block barriers, separate re/im LDS, PIDX padding.
// Measured R0: 54-57us, VGPR=104, no spill, VALUBusy ~30%.
__global__ __launch_bounds__(FT, 2) void conv_kernel(const float* __restrict__ a_t,
                                                     const float2* __restrict__ xt2,
                                                     float2* __restrict__ out_t2)
{
    __shared__ float re[8448];
    __shared__ float im[8448];
    const int tid = threadIdx.x;
    const int hd = blockIdx.x;
    const float JR = 0.9238795325f;        // e^{-2pi i/16}
    const float JI = -0.3826834324f;

    // ---- A forward: fused m=8192 stage (real input) ----
    {
        const float* src = a_t + (size_t)hd * N_FFT;
        float ck, sk;
        __sincosf(-6.283185307179586f / 8192.f * (float)tid, &sk, &ck);
#pragma unroll
        for (int pp = 0; pp < 4; ++pp) {
            int k = pp * FT + tid;
            float x0 = src[k], x1 = src[k + 2048], x2 = src[k + 4096], x3 = src[k + 6144];
            float ar = x0 + x2, br = x0 - x2;
            float cr = x1 + x3, e = x1 - x3;
            re[PIDX(k)] = ar + cr; im[PIDX(k)] = 0.f;
            float c1 = ck, s1 = sk;
            float c2 = c1 * c1 - s1 * s1, s2 = 2.f * c1 * s1;
            float c3 = c2 * c1 - s2 * s1, s3 = c2 * s1 + s2 * c1;
            re[PIDX(k + 2048)] = br * c1 + e * s1;  im[PIDX(k + 2048)] = br * s1 - e * c1;
            float t2r = ar - cr;
            re[PIDX(k + 4096)] = t2r * c2;          im[PIDX(k + 4096)] = t2r * s2;
            re[PIDX(k + 6144)] = br * c3 - e * s3;  im[PIDX(k + 6144)] = br * s3 + e * c3;
            float tc = ck * JR - sk * JI; sk = ck * JI + sk * JR; ck = tc;  // W^{k+512}
        }
    }
    __syncthreads();
    pass16_fwd<2048>(re, im, tid);
    __syncthreads();
    pass16_fwd<128>(re, im, tid);
    __syncthreads();
    // ---- A tail: unscaled spectrum stays in registers (1/N folded in later) ----
    float afr[16], afi[16];
    {
        const int base = tid * 16;
#pragma unroll
        for (int c = 0; c < 16; ++c) { int idx = PIDX(base + c); afr[c] = re[idx]; afi[c] = im[idx]; }
        fwd8(afr, afi, 0); fwd8(afr, afi, 8);
    }
    __syncthreads();
    // ---- Z forward: fused m=8192 stage (packed complex, x2=x3=0) ----
    {
        const float2* src = xt2 + (size_t)hd * N_SEQ;
        float ck, sk;
        __sincosf(-6.283185307179586f / 8192.f * (float)tid, &sk, &ck);
#pragma unroll
        for (int pp = 0; pp < 4; ++pp) {
            int k = pp * FT + tid;
            float2 z0 = src[k], z1 = src[k + 2048];
            float ar = z0.x, ai = z0.y;
            float cr = z1.x, ci = z1.y;
            float dr = z1.y, di = -z1.x;
            re[PIDX(k)] = ar + cr; im[PIDX(k)] = ai + ci;
            float c1 = ck, s1 = sk;
            float c2 = c1 * c1 - s1 * s1, s2 = 2.f * c1 * s1;
            float c3 = c2 * c1 - s2 * s1, s3 = c2 * s1 + s2 * c1;
            float t1r = ar + dr, t1i = ai + di;
            re[PIDX(k + 2048)] = t1r * c1 - t1i * s1; im[PIDX(k + 2048)] = t1r * s1 + t1i * c1;
            float t2r = ar - cr, t2i = ai - ci;
            re[PIDX(k + 4096)] = t2r * c2 - t2i * s2; im[PIDX(k + 4096)] = t2r * s2 + t2i * c2;
            float t3r = ar - dr, t3i = ai - di;
            re[PIDX(k + 6144)] = t3r * c3 - t3i * s3; im[PIDX(k + 6144)] = t3r * s3 + t3i * c3;
            float tc = ck * JR - sk * JI; sk = ck * JI + sk * JR; ck = tc;
        }
    }
    __syncthreads();
    pass16_fwd<2048>(re, im, tid);
    __syncthreads();
    pass16_fwd<128>(re, im, tid);
    __syncthreads();
    {   // Z tail + pointwise (af in regs, 1/N fused) + inverse head
        const int base = tid * 16;
        float zr[16], zi[16];
#pragma unroll
        for (int c = 0; c < 16; ++c) { int idx = PIDX(base + c); zr[c] = re[idx]; zi[c] = im[idx]; }
        fwd8(zr, zi, 0); fwd8(zr, zi, 8);
        const float inv = 1.0f / (float)N_FFT;
#pragma unroll
        for (int c = 0; c < 16; ++c) {
            float xr = zr[c], xi_ = zi[c];
            zr[c] = (xr * afr[c] - xi_ * afi[c]) * inv;
            zi[c] = (xr * afi[c] + xi_ * afr[c]) * inv;
        }
        inv8(zr, zi, 0); inv8(zr, zi, 8);
#pragma unroll
        for (int c = 0; c < 16; ++c) { int idx = PIDX(base + c); re[idx] = zr[c]; im[idx] = zi[c]; }
    }
    __syncthreads();
    pass16_inv<128>(re, im, tid);
    __syncthreads();
    pass16_inv<2048>(re, im, tid);
    __syncthreads();
    {   // fused final inverse stage (m=8192): store only [0,4096)
        float2* dst = out_t2 + (size_t)hd * N_SEQ;
        float ck, sk;
        __sincosf(6.283185307179586f / 8192.f * (float)tid, &sk, &ck);
        const float JcR = 0.9238795325f, JcI = 0.3826834324f;
#pragma unroll
        for (int pp = 0; pp < 4; ++pp) {
            int k = pp * FT + tid;
            float c1 = ck, s1 = sk;
            float c2 = c1 * c1 - s1 * s1, s2 = 2.f * c1 * s1;
            float c3 = c2 * c1 - s2 * s1, s3 = c2 * s1 + s2 * c1;
            float t0r = re[PIDX(k)],        t0i = im[PIDX(k)];
            float y1r = re[PIDX(k + 2048)], y1i = im[PIDX(k + 2048)];
            float y2r = re[PIDX(k + 4096)], y2i = im[PIDX(k + 4096)];
            float y3r = re[PIDX(k + 6144)], y3i = im[PIDX(k + 6144)];
            float t1r = y1r * c1 - y1i * s1, t1i = y1r * s1 + y1i * c1;
            float t2r = y2r * c2 - y2i * s2, t2i = y2r * s2 + y2i * c2;
            float t3r = y3r * c3 - y3i * s3, t3i = y3r * s3 + y3i * c3;
            float pr = t0r + t2r, pi = t0i + t2i;
            float qr = t0r - t2r, qi = t0i - t2i;
            float rr = t1r + t3r, ri = t1i + t3i;
            float sr = -(t1i - t3i), si = t1r - t3r;
            dst[k]        = make_float2(pr + rr, pi + ri);
            dst[k + 2048] = make_float2(qr + sr, qi + si);
            float tc = ck * JcR - sk * JcI; sk = ck * JcI + sk * JcR; ck = tc;
        }
    }
}

// ========== transpose out: out_t2[hd][n] -> out (2,8,N,64) ==========
__global__ __launch_bounds__(256) void transpose_o_kernel(const float2* __restrict__ out_t2,
                                                          float* __restrict__ out)
{
    __shared__ float t0[64][65];
    __shared__ float t1[64][65];
    int h = blockIdx.x >> 6;
    int nb = blockIdx.x & 63;
    int lx = threadIdx.x & 63;
    int ly = threadIdx.x >> 6;
    for (int r = ly; r < 64; r += 4) {
        float2 v = out_t2[(size_t)(h * 64 + r) * N_SEQ + nb * 64 + lx];
        t0[r][lx] = v.x;
        t1[r][lx] = v.y;
    }
    __syncthreads();
    float* d0 = out + ((size_t)h * N_SEQ + nb * 64) * 64;
    float* d1 = out + ((size_t)(8 + h) * N_SEQ + nb * 64) * 64;
    for (int r = ly; r < 64; r += 4) {
        d0[r * 64 + lx] = t0[lx][r];
        d1[r * 64 + lx] = t1[lx][r];
    }
}

extern "C" void kernel_launch(void* const* d_in, const int* in_sizes, int n_in,
                              void* d_out, int out_size, void* d_ws, size_t ws_size,
                              hipStream_t stream)
{
    const float* x     = (const float*)d_in[0];
    const float* w_in  = (const float*)d_in[1];
    const float* b_in  = (const float*)d_in[2];
    const float* w_hid = (const float*)d_in[3];
    const float* b_hid = (const float*)d_in[4];
    const float* w_out = (const float*)d_in[5];
    const float* b_out = (const float*)d_in[6];
    float* out = (float*)d_out;

    char* ws = (char*)d_ws;
    float2* xt2    = (float2*)ws;                               // 16 MB
    float*  a_t    = (float*)(ws + (size_t)16 * 1024 * 1024);   // 16 MB
    float2* out_t2 = (float2*)(ws + (size_t)32 * 1024 * 1024);  // 16 MB

    prep_kernel<<<768, 512, 0, stream>>>(x, w_in, b_in, w_hid, b_hid, w_out, b_out,
                                         a_t, xt2);
    conv_kernel<<<512, FT, 0, stream>>>(a_t, xt2, out_t2);
    transpose_o_kernel<<<512, 256, 0, stream>>>(out_t2, out);
}